// Round 9
// baseline (191.386 us; speedup 1.0000x reference)
//
#include <hip/hip_runtime.h>
#include <stdint.h>

#define NB 16
#define NA 8400
#define NA_PAD 9216
#define NCH 84
#define NCLS 80
#define CANDN 2048
#define MAXDET 300
#define NBIN 65536

typedef unsigned long long u64;

// ---------------- workspace layout (bytes) ----------------
static const size_t OFF_SU   = 0;        // 16*8400*4  = 537600 (u32 score keys)
static const size_t OFF_CLS  = 537600;   // 16*8400*4  = 537600
static const size_t OFF_HIST = 1075200;  // 16*65536*4 = 4194304
// total ~5.3 MB

// ---------- kernel 1: class max/argmax + u32 key + global 16-bit histogram ----------
__global__ __launch_bounds__(256) void score_kernel(const float* __restrict__ pred,
                                                    unsigned* __restrict__ sug,
                                                    int* __restrict__ cls,
                                                    int* __restrict__ hist) {
  int a = blockIdx.x * 256 + threadIdx.x;
  int b = blockIdx.y;
  if (a >= NA) return;
  const float* p = pred + (size_t)b * (NCH * NA) + 4 * NA + a;
  float best = p[0];
  int bc = 0;
#pragma unroll 8
  for (int c = 1; c < NCLS; ++c) {
    float v = p[(size_t)c * NA];
    if (v > best) { best = v; bc = c; }  // strict > : first-index argmax
  }
  unsigned u = ~__float_as_uint(best);  // ascending u == descending score
  sug[(size_t)b * NA + a] = u;
  cls[(size_t)b * NA + a] = bc;
  atomicAdd(&hist[b * NBIN + (int)(u >> 16)], 1);
}

__device__ inline u64 shflx64(u64 v, int m) {
  int lo = __shfl_xor((int)(unsigned)(v & 0xFFFFFFFFu), m, 64);
  int hi = __shfl_xor((int)(unsigned)(v >> 32), m, 64);
  return (((u64)(unsigned)hi) << 32) | (unsigned)lo;
}

__device__ inline u64 cswap(u64 a, u64 b, int s, int j, int kk) {
  bool low = (s & j) == 0;
  bool asc = (s & kk) == 0;
  bool takeMin = (low == asc);
  u64 mn = (a < b) ? a : b;
  u64 mx = (a < b) ? b : a;
  return takeMin ? mn : mx;
}

// exact division-free IoU>0.45f compare (25x24-bit f64 product is exact)
__device__ inline bool iou_gt(float4 bi, float ai, float4 bj, float aj) {
  const double THR = 0x1.CCCCCC8p-2;  // 0.45f + 2^-26 exactly
  float ix1 = fmaxf(bi.x, bj.x);
  float iy1 = fmaxf(bi.y, bj.y);
  float ix2 = fminf(bi.z, bj.z);
  float iy2 = fminf(bi.w, bj.w);
  float iw = fmaxf(__fsub_rn(ix2, ix1), 0.0f);
  float ih = fmaxf(__fsub_rn(iy2, iy1), 0.0f);
  float inter = __fmul_rn(iw, ih);
  float den = __fadd_rn(__fsub_rn(__fadd_rn(ai, aj), inter), 1e-7f);
  return (double)inter > THR * (double)den;
}

// ---------- kernel 2: fused hist-scan select + sort + prep + NMS + output ----------
__global__ __launch_bounds__(1024) void fused_kernel(const unsigned* __restrict__ sug,
                                                     const int* __restrict__ clsg,
                                                     const float* __restrict__ pred,
                                                     const int* __restrict__ imgsz,
                                                     const int* __restrict__ histg,
                                                     float* __restrict__ out) {
  __shared__ alignas(16) unsigned char smem[60928];
  __shared__ int hist8[256];
  __shared__ int cum[256];
  __shared__ int tielist[1024];
  __shared__ u64 vmask[32];
  __shared__ int wtot[16];
  __shared__ unsigned sh_pref;
  __shared__ int sh_k, sh_g, sh_cnt, sh_nms;

  // phase-A carve
  unsigned* su = (unsigned*)smem;              // [8400]  -> 33600
  u64* sortbuf = (u64*)(smem + 33600);         // [2048]  -> 49984
  // phase-B carve (live only after sort completes)
  float4* nmsb = (float4*)smem;                // [2048]  -> 32768
  float* areaA = (float*)(smem + 32768);       // [2048]  -> 40960
  u64* skey2 = (u64*)(smem + 40960);           // [2048]  -> 57344
  int* idxbuf = (int*)(smem + 57344);          // [300]   -> 58544
  u64* diag = (u64*)(smem + 58544);            // [256]   -> 60592
  u64* supm = (u64*)(smem + 60592);            // [32]    -> 60848

  int b = blockIdx.x;
  int tid = threadIdx.x;
  int lane = tid & 63;
  int wv = tid >> 6;

  if (tid == 0) { sh_g = 0; sh_cnt = 0; sh_nms = 0; }

  // ---- phase 0: scan global 65536-bin histogram -> top-16 prefix + k ----
  const int* hb = histg + b * NBIN;
  int base_t = tid * 64;
  int ssum = 0;
#pragma unroll
  for (int t = 0; t < 16; ++t) {
    int4 v = ((const int4*)(hb + base_t))[t];
    ssum += v.x + v.y + v.z + v.w;
  }
  int incl = ssum;
  for (int off = 1; off < 64; off <<= 1) {
    int t = __shfl_up(incl, off, 64);
    if (lane >= off) incl += t;
  }
  if (lane == 63) wtot[wv] = incl;
  __syncthreads();
  if (tid < 16) {
    int v = wtot[tid];
    int inc2 = v;
    for (int off = 1; off < 16; off <<= 1) {
      int t = __shfl_up(inc2, off, 16);
      if (tid >= off) inc2 += t;
    }
    wtot[tid] = inc2 - v;  // exclusive wave base
  }
  __syncthreads();
  int ebase = wtot[wv] + incl - ssum;  // exclusive base of this thread's 64 bins
  if (ebase < CANDN && ebase + ssum >= CANDN) {  // exactly one thread
    int c = ebase;
    for (int t = 0; t < 64; ++t) {
      int h = hb[base_t + t];
      if (c + h >= CANDN) { sh_pref = (unsigned)(base_t + t) << 16; sh_k = CANDN - c; break; }
      c += h;
    }
  }
  __syncthreads();
  unsigned prefix = sh_pref;
  int k = sh_k;

  // ---- phase 1: two 8-bit radix passes (first fused with global->LDS load) ----
  for (int shift = 8; shift >= 0; shift -= 8) {
    if (tid < 256) hist8[tid] = 0;
    __syncthreads();
    unsigned pmask = (shift == 8) ? 0xFFFF0000u : 0xFFFFFF00u;
    for (int i = tid; i < NA_PAD; i += 1024) {
      bool act = false;
      int d = 0;
      if (i < NA) {
        unsigned u;
        if (shift == 8) { u = sug[(size_t)b * NA + i]; su[i] = u; }
        else u = su[i];
        act = (u & pmask) == prefix;
        d = (int)((u >> shift) & 255);
      }
      u64 m = __ballot(act);
      if (m) {
#pragma unroll
        for (int bit = 0; bit < 8; ++bit) {
          u64 bb = __ballot((d >> bit) & 1);
          m &= ((d >> bit) & 1) ? bb : ~bb;
        }
        if (act && (m & ((1ULL << lane) - 1)) == 0ULL)
          atomicAdd(&hist8[d], (int)__popcll(m));
      }
    }
    __syncthreads();
    if (tid < 64) {  // inclusive scan of 256 bins
      int v0 = hist8[tid * 4 + 0], v1 = hist8[tid * 4 + 1];
      int v2 = hist8[tid * 4 + 2], v3 = hist8[tid * 4 + 3];
      int s0 = v0, s1 = s0 + v1, s2 = s1 + v2, s3 = s2 + v3;
      int tot = s3;
      for (int off = 1; off < 64; off <<= 1) {
        int t = __shfl_up(tot, off, 64);
        if (tid >= off) tot += t;
      }
      int base = tot - s3;
      cum[tid * 4 + 0] = base + s0;
      cum[tid * 4 + 1] = base + s1;
      cum[tid * 4 + 2] = base + s2;
      cum[tid * 4 + 3] = base + s3;
    }
    __syncthreads();
    if (tid < 256) {
      int c = cum[tid];
      int cprev = (tid == 0) ? 0 : cum[tid - 1];
      if (c >= k && cprev < k) {
        sh_pref = prefix | ((unsigned)tid << shift);
        sh_k = k - cprev;
      }
    }
    __syncthreads();
    prefix = sh_pref;
    k = sh_k;
  }
  unsigned ustar = prefix;
  int kp = k;

  // ---- phase 2: boundary tie-fix (rank by index) + compaction ----
  for (int i = tid; i < NA; i += 1024) {
    if (su[i] == ustar) {
      int p = atomicAdd(&sh_g, 1);
      if (p < 1024) tielist[p] = i;
    }
  }
  __syncthreads();
  int g = sh_g < 1024 ? sh_g : 1024;

  for (int i = tid; i < NA_PAD; i += 1024) {
    bool act = false;
    u64 key = 0;
    if (i < NA) {
      unsigned u = su[i];
      if (u < ustar) act = true;
      else if (u == ustar) {
        int r = 0;
        for (int t2 = 0; t2 < g; ++t2) r += (tielist[t2] < i);
        act = (r < kp);
      }
      key = (((u64)u) << 32) | (unsigned)i;
    }
    u64 mm = __ballot(act);
    if (mm) {
      int leader = __ffsll(mm) - 1;
      int base = 0;
      if (lane == leader) base = atomicAdd(&sh_cnt, (int)__popcll(mm));
      base = __shfl(base, leader, 64);
      if (act) sortbuf[base + (int)__popcll(mm & ((1ULL << lane) - 1))] = key;
    }
  }
  __syncthreads();

  // ---- phase 3: hybrid bitonic sort of 2048 u64 keys ----
  u64 e0 = sortbuf[tid];
  u64 e1 = sortbuf[tid + 1024];
  for (int kk = 2; kk <= CANDN; kk <<= 1) {
    for (int j = kk >> 1; j > 0; j >>= 1) {
      if (j == 1024) {
        u64 mn = (e0 < e1) ? e0 : e1;
        u64 mx = (e0 < e1) ? e1 : e0;
        e0 = mn; e1 = mx;
      } else if (j >= 64) {
        sortbuf[tid] = e0;
        sortbuf[tid + 1024] = e1;
        __syncthreads();
        u64 p0 = sortbuf[tid ^ j];
        u64 p1 = sortbuf[(tid + 1024) ^ j];
        e0 = cswap(e0, p0, tid, j, kk);
        e1 = cswap(e1, p1, tid + 1024, j, kk);
        __syncthreads();
      } else {
        u64 p0 = shflx64(e0, j);
        u64 p1 = shflx64(e1, j);
        e0 = cswap(e0, p0, tid, j, kk);
        e1 = cswap(e1, p1, tid + 1024, j, kk);
      }
    }
  }
  __syncthreads();  // sortbuf/su dead; phase-B carve takes over

  // ---- phase 4: prep ----
  const float* pb = pred + (size_t)b * (NCH * NA);
  float inv = (float)(1.0 / (double)imgsz[0]);
#pragma unroll
  for (int half = 0; half < 2; ++half) {
    u64 key = half ? e1 : e0;
    int s = tid + half * 1024;
    int idx = (int)(unsigned)(key & 0xFFFFFFFFu);
    float score = __uint_as_float(~(unsigned)(key >> 32));
    float x = pb[0 * NA + idx];
    float y = pb[1 * NA + idx];
    float w = pb[2 * NA + idx];
    float h = pb[3 * NA + idx];
    float hw = __fmul_rn(w, 0.5f);
    float hh = __fmul_rn(h, 0.5f);
    float x1 = __fsub_rn(x, hw);
    float y1 = __fsub_rn(y, hh);
    float x2 = __fadd_rn(x, hw);
    float y2 = __fadd_rn(y, hh);
    float clsf = (float)clsg[(size_t)b * NA + idx];
    float nx1 = __fadd_rn(__fmul_rn(x1, inv), clsf);
    float ny1 = __fadd_rn(__fmul_rn(y1, inv), clsf);
    float nx2 = __fadd_rn(__fmul_rn(x2, inv), clsf);
    float ny2 = __fadd_rn(__fmul_rn(y2, inv), clsf);
    float ar = __fmul_rn(__fsub_rn(nx2, nx1), __fsub_rn(ny2, ny1));
    nmsb[s] = make_float4(nx1, ny1, nx2, ny2);
    areaA[s] = ar;
    skey2[s] = key;
    u64 bal = __ballot(score > 0.25f);
    if (lane == 0) vmask[half * 16 + wv] = bal;
  }
  __syncthreads();

  // ---- phase 5: chunked NMS (chunk=128), IoU vs kept list + in-chunk diag ----
#pragma unroll 1
  for (int c = 0; c < 16; ++c) {
    __syncthreads();                 // kept list from prev chunk visible
    int nk0 = sh_nms;
    if (nk0 >= MAXDET) break;        // uniform
    int base = c << 7;
    float4 b0 = nmsb[base + lane];   float a0 = areaA[base + lane];        // row A
    float4 b1 = nmsb[base + 64 + lane]; float a1 = areaA[base + 64 + lane]; // row B
    // cross-chunk: both rows vs kept list (shared kept reads)
    bool supA = false, supB = false;
    for (int q = wv; q < nk0; q += 16) {
      int kq = idxbuf[q];
      float4 bk = nmsb[kq];
      float ak = areaA[kq];
      supA = supA || iou_gt(b0, a0, bk, ak);
      supB = supB || iou_gt(b1, a1, bk, ak);
    }
    u64 smA = __ballot(supA);
    u64 smB = __ballot(supB);
    if (lane == 0) { supm[wv] = smA; supm[16 + wv] = smB; }
    // in-chunk diag: wave wv owns rows 8wv..8wv+7 (of 128)
#pragma unroll
    for (int rr = 0; rr < 8; ++rr) {
      int r = (wv << 3) + rr;
      float4 bi = nmsb[base + r];
      float ai = areaA[base + r];
      bool s0 = iou_gt(bi, ai, b0, a0);
      bool s1 = iou_gt(bi, ai, b1, a1);
      u64 d0 = __ballot(s0);
      u64 d1 = __ballot(s1);
      if (lane == 0) { diag[2 * r] = d0; diag[2 * r + 1] = d1; }
    }
    __syncthreads();                 // supm/diag ready
    if (wv == 0) {                   // wave 0 resolves chunk greedily
      u64 orA = 0, orB = 0;
#pragma unroll
      for (int w = 0; w < 16; ++w) { orA |= supm[w]; orB |= supm[16 + w]; }
      bool tentA = (((vmask[2 * c] >> lane) & 1ULL) != 0ULL) &&
                   (((orA >> lane) & 1ULL) == 0ULL);
      bool tentB = (((vmask[2 * c + 1] >> lane) & 1ULL) != 0ULL) &&
                   (((orB >> lane) & 1ULL) == 0ULL);
      u64 cA0 = diag[2 * lane], cA1 = diag[2 * lane + 1];
      u64 cB0 = diag[2 * (64 + lane)], cB1 = diag[2 * (64 + lane) + 1];
      u64 kl0 = 0, kl1 = 0;
      int cnt = nk0;
      while (true) {
        bool aA = tentA && ((kl0 & cA0) == 0ULL) && ((kl1 & cA1) == 0ULL);
        bool aB = tentB && ((kl0 & cB0) == 0ULL) && ((kl1 & cB1) == 0ULL);
        u64 bbA = __ballot(aA);
        u64 bbB = __ballot(aB);
        if ((bbA | bbB) == 0ULL) break;
        int f = bbA ? (__ffsll(bbA) - 1) : (64 + __ffsll(bbB) - 1);
        if (f < 64) { kl0 |= 1ULL << f; tentA = tentA && (lane != f); }
        else { kl1 |= 1ULL << (f - 64); tentB = tentB && (lane != (f - 64)); }
        if (lane == 0) idxbuf[cnt] = base + f;
        cnt++;
        if (cnt >= MAXDET) break;
      }
      if (lane == 0) sh_nms = cnt;
    }
  }
  __syncthreads();

  // ---- phase 6: output (re-gather, identical rounding ops -> bit-exact) ----
  int total = sh_nms;
  if (tid < MAXDET) {
    float vals[6] = {0.f, 0.f, 0.f, 0.f, 0.f, 0.f};
    if (tid < total) {
      int gk = idxbuf[tid];
      u64 key = skey2[gk];
      int idx = (int)(unsigned)(key & 0xFFFFFFFFu);
      float score = __uint_as_float(~(unsigned)(key >> 32));
      float x = pb[0 * NA + idx];
      float y = pb[1 * NA + idx];
      float w = pb[2 * NA + idx];
      float h = pb[3 * NA + idx];
      float hw = __fmul_rn(w, 0.5f);
      float hh = __fmul_rn(h, 0.5f);
      vals[0] = __fsub_rn(x, hw);
      vals[1] = __fsub_rn(y, hh);
      vals[2] = __fadd_rn(x, hw);
      vals[3] = __fadd_rn(y, hh);
      vals[4] = score;
      vals[5] = (float)clsg[(size_t)b * NA + idx];
    }
#pragma unroll
    for (int q = 0; q < 6; ++q)
      out[((size_t)(b * MAXDET) + tid) * 6 + q] = vals[q];
  }
}

extern "C" void kernel_launch(void* const* d_in, const int* in_sizes, int n_in,
                              void* d_out, int out_size, void* d_ws, size_t ws_size,
                              hipStream_t stream) {
  (void)in_sizes; (void)n_in; (void)out_size; (void)ws_size;
  const float* pred = (const float*)d_in[0];
  const int* imgsz = (const int*)d_in[1];
  char* ws = (char*)d_ws;
  unsigned* sug = (unsigned*)(ws + OFF_SU);
  int* cls = (int*)(ws + OFF_CLS);
  int* hist = (int*)(ws + OFF_HIST);
  float* out = (float*)d_out;

  hipMemsetAsync(hist, 0, (size_t)NB * NBIN * sizeof(int), stream);
  score_kernel<<<dim3((NA + 255) / 256, NB), 256, 0, stream>>>(pred, sug, cls, hist);
  fused_kernel<<<NB, 1024, 0, stream>>>(sug, cls, pred, imgsz, hist, out);
}

// Round 10
// 132.234 us; speedup vs baseline: 1.4473x; 1.4473x over previous
//
#include <hip/hip_runtime.h>
#include <stdint.h>

#define NB 16
#define NA 8400
#define NA_PAD 9216
#define NCH 84
#define NCLS 80
#define CANDN 2048
#define MAXDET 300

typedef unsigned long long u64;

// ---------------- workspace layout (bytes) ----------------
static const size_t OFF_SU  = 0;         // 16*8400*4  = 537600 (u32 score keys)
static const size_t OFF_CLS = 537600;    // 16*8400*4  = 537600
static const size_t OFF_BOX = 1075200;   // 16*8400*16 = 2150400 (xywh float4)
// total ~3.2 MB

// ---------- kernel 1: class max/argmax + u32 key + transposed box gather ----------
__global__ __launch_bounds__(256) void score_kernel(const float* __restrict__ pred,
                                                    unsigned* __restrict__ sug,
                                                    int* __restrict__ cls,
                                                    float4* __restrict__ boxT) {
  int a = blockIdx.x * 256 + threadIdx.x;
  int b = blockIdx.y;
  if (a >= NA) return;
  const float* pbase = pred + (size_t)b * (NCH * NA);
  const float* p = pbase + 4 * NA + a;
  float best = p[0];
  int bc = 0;
#pragma unroll 8
  for (int c = 1; c < NCLS; ++c) {
    float v = p[(size_t)c * NA];
    if (v > best) { best = v; bc = c; }  // strict > : first-index argmax
  }
  sug[(size_t)b * NA + a] = ~__float_as_uint(best);  // ascending u == desc score
  cls[(size_t)b * NA + a] = bc;
  boxT[(size_t)b * NA + a] =
      make_float4(pbase[a], pbase[NA + a], pbase[2 * NA + a], pbase[3 * NA + a]);
}

__device__ inline u64 shflx64(u64 v, int m) {
  int lo = __shfl_xor((int)(unsigned)(v & 0xFFFFFFFFu), m, 64);
  int hi = __shfl_xor((int)(unsigned)(v >> 32), m, 64);
  return (((u64)(unsigned)hi) << 32) | (unsigned)lo;
}

__device__ inline u64 cswap(u64 a, u64 b, int s, int j, int kk) {
  bool low = (s & j) == 0;
  bool asc = (s & kk) == 0;
  bool takeMin = (low == asc);
  u64 mn = (a < b) ? a : b;
  u64 mx = (a < b) ? b : a;
  return takeMin ? mn : mx;
}

// exact division-free IoU>0.45f compare (25x24-bit f64 product is exact)
__device__ inline bool iou_gt(float4 bi, float ai, float4 bj, float aj) {
  const double THR = 0x1.CCCCCC8p-2;  // 0.45f + 2^-26 exactly
  float ix1 = fmaxf(bi.x, bj.x);
  float iy1 = fmaxf(bi.y, bj.y);
  float ix2 = fminf(bi.z, bj.z);
  float iy2 = fminf(bi.w, bj.w);
  float iw = fmaxf(__fsub_rn(ix2, ix1), 0.0f);
  float ih = fmaxf(__fsub_rn(iy2, iy1), 0.0f);
  float inter = __fmul_rn(iw, ih);
  float den = __fadd_rn(__fsub_rn(__fadd_rn(ai, aj), inter), 1e-7f);
  return (double)inter > THR * (double)den;
}

// ---------- kernel 2: fused select + sort + prep + NMS + output ----------
__global__ __launch_bounds__(1024) void fused_kernel(const unsigned* __restrict__ sug,
                                                     const int* __restrict__ clsg,
                                                     const float4* __restrict__ boxTg,
                                                     const int* __restrict__ imgsz,
                                                     float* __restrict__ out) {
  __shared__ alignas(16) unsigned char smem[60928];
  __shared__ int hist8[256];
  __shared__ int cum[256];
  __shared__ int tielist[1024];
  __shared__ u64 vmask[32];
  __shared__ unsigned sh_pref;
  __shared__ int sh_k, sh_g, sh_cnt, sh_nms;

  // phase-A carve
  unsigned* su = (unsigned*)smem;              // [8400]  -> 33600
  u64* sortbuf = (u64*)(smem + 33600);         // [2048]  -> 49984
  // phase-B carve (live only after sort completes)
  float4* nmsb = (float4*)smem;                // [2048]  -> 32768
  float* areaA = (float*)(smem + 32768);       // [2048]  -> 40960
  u64* skey2 = (u64*)(smem + 40960);           // [2048]  -> 57344
  int* idxbuf = (int*)(smem + 57344);          // [300]   -> 58544
  u64* diag = (u64*)(smem + 58544);            // [256]   -> 60592
  u64* supm = (u64*)(smem + 60592);            // [32]    -> 60848

  int b = blockIdx.x;
  int tid = threadIdx.x;
  int lane = tid & 63;
  int wv = tid >> 6;

  if (tid == 0) { sh_pref = 0; sh_k = CANDN; sh_g = 0; sh_cnt = 0; sh_nms = 0; }

  // ---- phase 0: vectorized su preload (2100 uint4 loads, high MLP) ----
  {
    uint4* su4 = (uint4*)su;
    const uint4* sg4 = (const uint4*)(sug + (size_t)b * NA);
    for (int v = tid; v < NA / 4; v += 1024) su4[v] = sg4[v];
  }
  __syncthreads();

  // ---- phase 1: 4-pass radix select on u (all passes from LDS) ----
  unsigned prefix = 0;
  int k = CANDN;
  for (int shift = 24; shift >= 0; shift -= 8) {
    if (tid < 256) hist8[tid] = 0;
    __syncthreads();
    unsigned pmask = (shift == 24) ? 0u : (0xFFFFFFFFu << (shift + 8));
    for (int i = tid; i < NA_PAD; i += 1024) {
      bool act = false;
      int d = 0;
      if (i < NA) {
        unsigned u = su[i];
        act = (u & pmask) == prefix;
        d = (int)((u >> shift) & 255);
      }
      // wave-aggregate same-digit counts (scores cluster -> few hot bins)
      u64 m = __ballot(act);
      if (m) {
#pragma unroll
        for (int bit = 0; bit < 8; ++bit) {
          u64 bb = __ballot((d >> bit) & 1);
          m &= ((d >> bit) & 1) ? bb : ~bb;
        }
        if (act && (m & ((1ULL << lane) - 1)) == 0ULL)
          atomicAdd(&hist8[d], (int)__popcll(m));
      }
    }
    __syncthreads();
    if (tid < 64) {  // inclusive scan of 256 bins
      int v0 = hist8[tid * 4 + 0], v1 = hist8[tid * 4 + 1];
      int v2 = hist8[tid * 4 + 2], v3 = hist8[tid * 4 + 3];
      int s0 = v0, s1 = s0 + v1, s2 = s1 + v2, s3 = s2 + v3;
      int tot = s3;
      for (int off = 1; off < 64; off <<= 1) {
        int t = __shfl_up(tot, off, 64);
        if (tid >= off) tot += t;
      }
      int base = tot - s3;
      cum[tid * 4 + 0] = base + s0;
      cum[tid * 4 + 1] = base + s1;
      cum[tid * 4 + 2] = base + s2;
      cum[tid * 4 + 3] = base + s3;
    }
    __syncthreads();
    if (tid < 256) {
      int c = cum[tid];
      int cprev = (tid == 0) ? 0 : cum[tid - 1];
      if (c >= k && cprev < k) {
        sh_pref = prefix | ((unsigned)tid << shift);
        sh_k = k - cprev;
      }
    }
    __syncthreads();
    prefix = sh_pref;
    k = sh_k;
  }
  unsigned ustar = prefix;
  int kp = k;

  // ---- phase 2: boundary tie-fix (rank by index) + compaction ----
  for (int i = tid; i < NA; i += 1024) {
    if (su[i] == ustar) {
      int p = atomicAdd(&sh_g, 1);
      if (p < 1024) tielist[p] = i;
    }
  }
  __syncthreads();
  int g = sh_g < 1024 ? sh_g : 1024;

  for (int i = tid; i < NA_PAD; i += 1024) {
    bool act = false;
    u64 key = 0;
    if (i < NA) {
      unsigned u = su[i];
      if (u < ustar) act = true;
      else if (u == ustar) {
        int r = 0;
        for (int t2 = 0; t2 < g; ++t2) r += (tielist[t2] < i);
        act = (r < kp);
      }
      key = (((u64)u) << 32) | (unsigned)i;
    }
    u64 mm = __ballot(act);
    if (mm) {
      int leader = __ffsll(mm) - 1;
      int base = 0;
      if (lane == leader) base = atomicAdd(&sh_cnt, (int)__popcll(mm));
      base = __shfl(base, leader, 64);
      if (act) sortbuf[base + (int)__popcll(mm & ((1ULL << lane) - 1))] = key;
    }
  }
  __syncthreads();

  // ---- phase 3: hybrid bitonic sort of 2048 u64 keys ----
  u64 e0 = sortbuf[tid];
  u64 e1 = sortbuf[tid + 1024];
  for (int kk = 2; kk <= CANDN; kk <<= 1) {
    for (int j = kk >> 1; j > 0; j >>= 1) {
      if (j == 1024) {
        u64 mn = (e0 < e1) ? e0 : e1;
        u64 mx = (e0 < e1) ? e1 : e0;
        e0 = mn; e1 = mx;
      } else if (j >= 64) {
        sortbuf[tid] = e0;
        sortbuf[tid + 1024] = e1;
        __syncthreads();
        u64 p0 = sortbuf[tid ^ j];
        u64 p1 = sortbuf[(tid + 1024) ^ j];
        e0 = cswap(e0, p0, tid, j, kk);
        e1 = cswap(e1, p1, tid + 1024, j, kk);
        __syncthreads();
      } else {
        u64 p0 = shflx64(e0, j);
        u64 p1 = shflx64(e1, j);
        e0 = cswap(e0, p0, tid, j, kk);
        e1 = cswap(e1, p1, tid + 1024, j, kk);
      }
    }
  }
  __syncthreads();  // sortbuf/su dead; phase-B carve takes over

  // ---- phase 4: prep (1 float4 + 1 int gather per candidate) ----
  const float4* bT = boxTg + (size_t)b * NA;
  float inv = (float)(1.0 / (double)imgsz[0]);
#pragma unroll
  for (int half = 0; half < 2; ++half) {
    u64 key = half ? e1 : e0;
    int s = tid + half * 1024;
    int idx = (int)(unsigned)(key & 0xFFFFFFFFu);
    float score = __uint_as_float(~(unsigned)(key >> 32));
    float4 bx = bT[idx];
    float hw = __fmul_rn(bx.z, 0.5f);
    float hh = __fmul_rn(bx.w, 0.5f);
    float x1 = __fsub_rn(bx.x, hw);
    float y1 = __fsub_rn(bx.y, hh);
    float x2 = __fadd_rn(bx.x, hw);
    float y2 = __fadd_rn(bx.y, hh);
    float clsf = (float)clsg[(size_t)b * NA + idx];
    float nx1 = __fadd_rn(__fmul_rn(x1, inv), clsf);
    float ny1 = __fadd_rn(__fmul_rn(y1, inv), clsf);
    float nx2 = __fadd_rn(__fmul_rn(x2, inv), clsf);
    float ny2 = __fadd_rn(__fmul_rn(y2, inv), clsf);
    float ar = __fmul_rn(__fsub_rn(nx2, nx1), __fsub_rn(ny2, ny1));
    nmsb[s] = make_float4(nx1, ny1, nx2, ny2);
    areaA[s] = ar;
    skey2[s] = key;
    u64 bal = __ballot(score > 0.25f);
    if (lane == 0) vmask[half * 16 + wv] = bal;
  }
  __syncthreads();

  // ---- phase 5: chunked NMS (chunk=128), IoU vs kept list + in-chunk diag ----
#pragma unroll 1
  for (int c = 0; c < 16; ++c) {
    __syncthreads();                 // kept list from prev chunk visible
    int nk0 = sh_nms;
    if (nk0 >= MAXDET) break;        // uniform
    int base = c << 7;
    float4 b0 = nmsb[base + lane];   float a0 = areaA[base + lane];         // row A
    float4 b1 = nmsb[base + 64 + lane]; float a1 = areaA[base + 64 + lane]; // row B
    // cross-chunk: both rows vs kept list (shared kept reads)
    bool supA = false, supB = false;
    for (int q = wv; q < nk0; q += 16) {
      int kq = idxbuf[q];
      float4 bk = nmsb[kq];
      float ak = areaA[kq];
      supA = supA || iou_gt(b0, a0, bk, ak);
      supB = supB || iou_gt(b1, a1, bk, ak);
    }
    u64 smA = __ballot(supA);
    u64 smB = __ballot(supB);
    if (lane == 0) { supm[wv] = smA; supm[16 + wv] = smB; }
    // in-chunk diag: wave wv owns rows 8wv..8wv+7 (of 128)
#pragma unroll
    for (int rr = 0; rr < 8; ++rr) {
      int r = (wv << 3) + rr;
      float4 bi = nmsb[base + r];
      float ai = areaA[base + r];
      bool s0 = iou_gt(bi, ai, b0, a0);
      bool s1 = iou_gt(bi, ai, b1, a1);
      u64 d0 = __ballot(s0);
      u64 d1 = __ballot(s1);
      if (lane == 0) { diag[2 * r] = d0; diag[2 * r + 1] = d1; }
    }
    __syncthreads();                 // supm/diag ready
    if (wv == 0) {                   // wave 0 resolves chunk greedily
      u64 orA = 0, orB = 0;
#pragma unroll
      for (int w = 0; w < 16; ++w) { orA |= supm[w]; orB |= supm[16 + w]; }
      bool tentA = (((vmask[2 * c] >> lane) & 1ULL) != 0ULL) &&
                   (((orA >> lane) & 1ULL) == 0ULL);
      bool tentB = (((vmask[2 * c + 1] >> lane) & 1ULL) != 0ULL) &&
                   (((orB >> lane) & 1ULL) == 0ULL);
      u64 cA0 = diag[2 * lane], cA1 = diag[2 * lane + 1];
      u64 cB0 = diag[2 * (64 + lane)], cB1 = diag[2 * (64 + lane) + 1];
      u64 kl0 = 0, kl1 = 0;
      int cnt = nk0;
      while (true) {
        bool aA = tentA && ((kl0 & cA0) == 0ULL) && ((kl1 & cA1) == 0ULL);
        bool aB = tentB && ((kl0 & cB0) == 0ULL) && ((kl1 & cB1) == 0ULL);
        u64 bbA = __ballot(aA);
        u64 bbB = __ballot(aB);
        if ((bbA | bbB) == 0ULL) break;
        int f = bbA ? (__ffsll(bbA) - 1) : (64 + __ffsll(bbB) - 1);
        if (f < 64) { kl0 |= 1ULL << f; tentA = tentA && (lane != f); }
        else { kl1 |= 1ULL << (f - 64); tentB = tentB && (lane != (f - 64)); }
        if (lane == 0) idxbuf[cnt] = base + f;
        cnt++;
        if (cnt >= MAXDET) break;
      }
      if (lane == 0) sh_nms = cnt;
    }
  }
  __syncthreads();

  // ---- phase 6: output (re-gather, identical rounding ops -> bit-exact) ----
  int total = sh_nms;
  if (tid < MAXDET) {
    float vals[6] = {0.f, 0.f, 0.f, 0.f, 0.f, 0.f};
    if (tid < total) {
      int gk = idxbuf[tid];
      u64 key = skey2[gk];
      int idx = (int)(unsigned)(key & 0xFFFFFFFFu);
      float score = __uint_as_float(~(unsigned)(key >> 32));
      float4 bx = bT[idx];
      float hw = __fmul_rn(bx.z, 0.5f);
      float hh = __fmul_rn(bx.w, 0.5f);
      vals[0] = __fsub_rn(bx.x, hw);
      vals[1] = __fsub_rn(bx.y, hh);
      vals[2] = __fadd_rn(bx.x, hw);
      vals[3] = __fadd_rn(bx.y, hh);
      vals[4] = score;
      vals[5] = (float)clsg[(size_t)b * NA + idx];
    }
#pragma unroll
    for (int q = 0; q < 6; ++q)
      out[((size_t)(b * MAXDET) + tid) * 6 + q] = vals[q];
  }
}

extern "C" void kernel_launch(void* const* d_in, const int* in_sizes, int n_in,
                              void* d_out, int out_size, void* d_ws, size_t ws_size,
                              hipStream_t stream) {
  (void)in_sizes; (void)n_in; (void)out_size; (void)ws_size;
  const float* pred = (const float*)d_in[0];
  const int* imgsz = (const int*)d_in[1];
  char* ws = (char*)d_ws;
  unsigned* sug = (unsigned*)(ws + OFF_SU);
  int* cls = (int*)(ws + OFF_CLS);
  float4* boxT = (float4*)(ws + OFF_BOX);
  float* out = (float*)d_out;

  score_kernel<<<dim3((NA + 255) / 256, NB), 256, 0, stream>>>(pred, sug, cls, boxT);
  fused_kernel<<<NB, 1024, 0, stream>>>(sug, cls, boxT, imgsz, out);
}

// Round 11
// 105.129 us; speedup vs baseline: 1.8205x; 1.2578x over previous
//
#include <hip/hip_runtime.h>
#include <stdint.h>

#define NB 16
#define NA 8400
#define NA_PAD 9216
#define NCH 84
#define NCLS 80
#define CANDN 2048
#define MAXDET 300

typedef unsigned long long u64;

// ---------------- workspace layout (bytes) ----------------
static const size_t OFF_SU  = 0;         // 16*8400*4  = 537600 (u32 score keys)
static const size_t OFF_CLS = 537600;    // 16*8400*4  = 537600
static const size_t OFF_BOX = 1075200;   // 16*8400*16 = 2150400 (xywh float4)
// total ~3.2 MB

// ---------- kernel 1: class max/argmax + u32 key + transposed box gather ----------
__global__ __launch_bounds__(256) void score_kernel(const float* __restrict__ pred,
                                                    unsigned* __restrict__ sug,
                                                    int* __restrict__ cls,
                                                    float4* __restrict__ boxT) {
  int a = blockIdx.x * 256 + threadIdx.x;
  int b = blockIdx.y;
  if (a >= NA) return;
  const float* pbase = pred + (size_t)b * (NCH * NA);
  const float* p = pbase + 4 * NA + a;
  float best = p[0];
  int bc = 0;
#pragma unroll 8
  for (int c = 1; c < NCLS; ++c) {
    float v = p[(size_t)c * NA];
    if (v > best) { best = v; bc = c; }  // strict > : first-index argmax
  }
  sug[(size_t)b * NA + a] = ~__float_as_uint(best);  // ascending u == desc score
  cls[(size_t)b * NA + a] = bc;
  boxT[(size_t)b * NA + a] =
      make_float4(pbase[a], pbase[NA + a], pbase[2 * NA + a], pbase[3 * NA + a]);
}

__device__ inline u64 shflx64(u64 v, int m) {
  int lo = __shfl_xor((int)(unsigned)(v & 0xFFFFFFFFu), m, 64);
  int hi = __shfl_xor((int)(unsigned)(v >> 32), m, 64);
  return (((u64)(unsigned)hi) << 32) | (unsigned)lo;
}

__device__ inline u64 cswap(u64 a, u64 b, int s, int j, int kk) {
  bool low = (s & j) == 0;
  bool asc = (s & kk) == 0;
  bool takeMin = (low == asc);
  u64 mn = (a < b) ? a : b;
  u64 mx = (a < b) ? b : a;
  return takeMin ? mn : mx;
}

// exact division-free IoU>0.45f compare (25x24-bit f64 product is exact)
__device__ inline bool iou_gt(float4 bi, float ai, float4 bj, float aj) {
  const double THR = 0x1.CCCCCC8p-2;  // 0.45f + 2^-26 exactly
  float ix1 = fmaxf(bi.x, bj.x);
  float iy1 = fmaxf(bi.y, bj.y);
  float ix2 = fminf(bi.z, bj.z);
  float iy2 = fminf(bi.w, bj.w);
  float iw = fmaxf(__fsub_rn(ix2, ix1), 0.0f);
  float ih = fmaxf(__fsub_rn(iy2, iy1), 0.0f);
  float inter = __fmul_rn(iw, ih);
  float den = __fadd_rn(__fsub_rn(__fadd_rn(ai, aj), inter), 1e-7f);
  return (double)inter > THR * (double)den;
}

// ---------- kernel 2: fused select + sort + prep + NMS + output ----------
__global__ __launch_bounds__(1024) void fused_kernel(const unsigned* __restrict__ sug,
                                                     const int* __restrict__ clsg,
                                                     const float4* __restrict__ boxTg,
                                                     const int* __restrict__ imgsz,
                                                     float* __restrict__ out) {
  __shared__ alignas(16) unsigned char smem[65280];
  __shared__ int hist8[256];
  __shared__ int cum[256];
  __shared__ int tielist[1024];
  __shared__ u64 vmask[32];
  __shared__ unsigned sh_pref;
  __shared__ int sh_k, sh_g, sh_cnt, sh_nms;

  // phase-A carve
  unsigned* su = (unsigned*)smem;              // [8400]  -> 33600
  u64* sortbuf = (u64*)(smem + 33600);         // [2048]  -> 49984
  // phase-B carve (live only after sort completes)
  float4* nmsb = (float4*)smem;                // [2048]  -> 32768
  float* areaA = (float*)(smem + 32768);       // [2048]  -> 40960
  u64* skey2 = (u64*)(smem + 40960);           // [2048]  -> 57344
  float4* keptbox = (float4*)(smem + 57344);   // [300]   -> 62144
  float* keptarea = (float*)(smem + 62144);    // [300]   -> 63344
  int* idxbuf = (int*)(smem + 63344);          // [300]   -> 64544
  u64* diag = (u64*)(smem + 64544);            // [64]    -> 65056
  u64* supm = (u64*)(smem + 65056);            // [16]    -> 65184

  int b = blockIdx.x;
  int tid = threadIdx.x;
  int lane = tid & 63;
  int wv = tid >> 6;

  if (tid == 0) { sh_pref = 0; sh_k = CANDN; sh_g = 0; sh_cnt = 0; sh_nms = 0; }

  // ---- phase 0: vectorized su preload (2100 uint4 loads, high MLP) ----
  {
    uint4* su4 = (uint4*)su;
    const uint4* sg4 = (const uint4*)(sug + (size_t)b * NA);
    for (int v = tid; v < NA / 4; v += 1024) su4[v] = sg4[v];
  }
  __syncthreads();

  // ---- phase 1: 4-pass radix select on u (all passes from LDS) ----
  unsigned prefix = 0;
  int k = CANDN;
  for (int shift = 24; shift >= 0; shift -= 8) {
    if (tid < 256) hist8[tid] = 0;
    __syncthreads();
    unsigned pmask = (shift == 24) ? 0u : (0xFFFFFFFFu << (shift + 8));
    for (int i = tid; i < NA_PAD; i += 1024) {
      bool act = false;
      int d = 0;
      if (i < NA) {
        unsigned u = su[i];
        act = (u & pmask) == prefix;
        d = (int)((u >> shift) & 255);
      }
      // wave-aggregate same-digit counts (scores cluster -> few hot bins)
      u64 m = __ballot(act);
      if (m) {
#pragma unroll
        for (int bit = 0; bit < 8; ++bit) {
          u64 bb = __ballot((d >> bit) & 1);
          m &= ((d >> bit) & 1) ? bb : ~bb;
        }
        if (act && (m & ((1ULL << lane) - 1)) == 0ULL)
          atomicAdd(&hist8[d], (int)__popcll(m));
      }
    }
    __syncthreads();
    if (tid < 64) {  // inclusive scan of 256 bins
      int v0 = hist8[tid * 4 + 0], v1 = hist8[tid * 4 + 1];
      int v2 = hist8[tid * 4 + 2], v3 = hist8[tid * 4 + 3];
      int s0 = v0, s1 = s0 + v1, s2 = s1 + v2, s3 = s2 + v3;
      int tot = s3;
      for (int off = 1; off < 64; off <<= 1) {
        int t = __shfl_up(tot, off, 64);
        if (tid >= off) tot += t;
      }
      int base = tot - s3;
      cum[tid * 4 + 0] = base + s0;
      cum[tid * 4 + 1] = base + s1;
      cum[tid * 4 + 2] = base + s2;
      cum[tid * 4 + 3] = base + s3;
    }
    __syncthreads();
    if (tid < 256) {
      int c = cum[tid];
      int cprev = (tid == 0) ? 0 : cum[tid - 1];
      if (c >= k && cprev < k) {
        sh_pref = prefix | ((unsigned)tid << shift);
        sh_k = k - cprev;
      }
    }
    __syncthreads();
    prefix = sh_pref;
    k = sh_k;
  }
  unsigned ustar = prefix;
  int kp = k;

  // ---- phase 2: boundary tie-fix (rank by index) + compaction ----
  for (int i = tid; i < NA; i += 1024) {
    if (su[i] == ustar) {
      int p = atomicAdd(&sh_g, 1);
      if (p < 1024) tielist[p] = i;
    }
  }
  __syncthreads();
  int g = sh_g < 1024 ? sh_g : 1024;

  for (int i = tid; i < NA_PAD; i += 1024) {
    bool act = false;
    u64 key = 0;
    if (i < NA) {
      unsigned u = su[i];
      if (u < ustar) act = true;
      else if (u == ustar) {
        int r = 0;
        for (int t2 = 0; t2 < g; ++t2) r += (tielist[t2] < i);
        act = (r < kp);
      }
      key = (((u64)u) << 32) | (unsigned)i;
    }
    u64 mm = __ballot(act);
    if (mm) {
      int leader = __ffsll(mm) - 1;
      int base = 0;
      if (lane == leader) base = atomicAdd(&sh_cnt, (int)__popcll(mm));
      base = __shfl(base, leader, 64);
      if (act) sortbuf[base + (int)__popcll(mm & ((1ULL << lane) - 1))] = key;
    }
  }
  __syncthreads();

  // ---- phase 3: hybrid bitonic sort of 2048 u64 keys ----
  u64 e0 = sortbuf[tid];
  u64 e1 = sortbuf[tid + 1024];
  for (int kk = 2; kk <= CANDN; kk <<= 1) {
    for (int j = kk >> 1; j > 0; j >>= 1) {
      if (j == 1024) {
        u64 mn = (e0 < e1) ? e0 : e1;
        u64 mx = (e0 < e1) ? e1 : e0;
        e0 = mn; e1 = mx;
      } else if (j >= 64) {
        sortbuf[tid] = e0;
        sortbuf[tid + 1024] = e1;
        __syncthreads();
        u64 p0 = sortbuf[tid ^ j];
        u64 p1 = sortbuf[(tid + 1024) ^ j];
        e0 = cswap(e0, p0, tid, j, kk);
        e1 = cswap(e1, p1, tid + 1024, j, kk);
        __syncthreads();
      } else {
        u64 p0 = shflx64(e0, j);
        u64 p1 = shflx64(e1, j);
        e0 = cswap(e0, p0, tid, j, kk);
        e1 = cswap(e1, p1, tid + 1024, j, kk);
      }
    }
  }
  __syncthreads();  // sortbuf/su dead; phase-B carve takes over

  // ---- phase 4: prep (1 float4 + 1 int gather per candidate) ----
  const float4* bT = boxTg + (size_t)b * NA;
  float inv = (float)(1.0 / (double)imgsz[0]);
#pragma unroll
  for (int half = 0; half < 2; ++half) {
    u64 key = half ? e1 : e0;
    int s = tid + half * 1024;
    int idx = (int)(unsigned)(key & 0xFFFFFFFFu);
    float score = __uint_as_float(~(unsigned)(key >> 32));
    float4 bx = bT[idx];
    float hw = __fmul_rn(bx.z, 0.5f);
    float hh = __fmul_rn(bx.w, 0.5f);
    float x1 = __fsub_rn(bx.x, hw);
    float y1 = __fsub_rn(bx.y, hh);
    float x2 = __fadd_rn(bx.x, hw);
    float y2 = __fadd_rn(bx.y, hh);
    float clsf = (float)clsg[(size_t)b * NA + idx];
    float nx1 = __fadd_rn(__fmul_rn(x1, inv), clsf);
    float ny1 = __fadd_rn(__fmul_rn(y1, inv), clsf);
    float nx2 = __fadd_rn(__fmul_rn(x2, inv), clsf);
    float ny2 = __fadd_rn(__fmul_rn(y2, inv), clsf);
    float ar = __fmul_rn(__fsub_rn(nx2, nx1), __fsub_rn(ny2, ny1));
    nmsb[s] = make_float4(nx1, ny1, nx2, ny2);
    areaA[s] = ar;
    skey2[s] = key;
    u64 bal = __ballot(score > 0.25f);
    if (lane == 0) vmask[half * 16 + wv] = bal;
  }
  __syncthreads();

  // ---- phase 5: chunked NMS (chunk=64), cross via dense kept list ----
  // Cross-chunk suppression checks row vs KEPT boxes only, read from the
  // dense keptbox[] array (affine addresses -> pipelined ds_reads, no
  // idxbuf->nmsb double-hop). Wave 0 appends new keeps at resolve time.
#pragma unroll 1
  for (int c = 0; c < 32; ++c) {
    __syncthreads();                 // kept list from prev chunk visible
    int nk0 = sh_nms;
    if (nk0 >= MAXDET) break;        // uniform
    int rg = (c << 6) + lane;
    float4 br = nmsb[rg];            // this thread's row box (lane = row)
    float arr = areaA[rg];
    // cross-chunk: row vs dense kept list, strided over 16 waves
    bool sup = false;
    for (int q = wv; q < nk0; q += 16)
      sup = sup || iou_gt(br, arr, keptbox[q], keptarea[q]);
    u64 sm = __ballot(sup);
    if (lane == 0) supm[wv] = sm;
    // in-chunk diag: wave wv computes rows 4wv..4wv+3 vs all 64 lanes
#pragma unroll
    for (int rr = 0; rr < 4; ++rr) {
      int r = (wv << 2) + rr;
      float4 bi = nmsb[(c << 6) + r];
      float ai = areaA[(c << 6) + r];
      bool supd = iou_gt(bi, ai, br, arr);
      u64 bb = __ballot(supd);
      if (lane == 0) diag[r] = bb;
    }
    __syncthreads();                 // supm/diag ready
    if (wv == 0) {                   // wave 0 resolves chunk c greedily
      u64 orsup = 0ULL;
#pragma unroll
      for (int w = 0; w < 16; ++w) orsup |= supm[w];
      bool tent = (((vmask[c] >> lane) & 1ULL) != 0ULL) &&
                  (((orsup >> lane) & 1ULL) == 0ULL);
      u64 col = diag[lane];          // bit k: in-chunk k suppresses me
      u64 keptloc = 0ULL;
      int cnt = nk0;
      while (true) {
        bool alive = tent && ((keptloc & col) == 0ULL);
        u64 bb = __ballot(alive);
        if (bb == 0ULL) break;
        int f = __ffsll(bb) - 1;     // lowest alive = next greedy keep
        keptloc |= (1ULL << f);
        tent = tent && (lane != f);  // self-clear (diagonal may be 0)
        if (lane == 0) idxbuf[cnt] = (c << 6) + f;
        cnt++;
        if (cnt >= MAXDET) break;
      }
      if (lane == 0) sh_nms = cnt;
      // append this chunk's keeps to the dense kept arrays (lane-parallel)
      for (int q = nk0 + lane; q < cnt; q += 64) {
        int gk = idxbuf[q];
        keptbox[q] = nmsb[gk];
        keptarea[q] = areaA[gk];
      }
    }
  }
  __syncthreads();

  // ---- phase 6: output (re-gather, identical rounding ops -> bit-exact) ----
  int total = sh_nms;
  if (tid < MAXDET) {
    float vals[6] = {0.f, 0.f, 0.f, 0.f, 0.f, 0.f};
    if (tid < total) {
      int gk = idxbuf[tid];
      u64 key = skey2[gk];
      int idx = (int)(unsigned)(key & 0xFFFFFFFFu);
      float score = __uint_as_float(~(unsigned)(key >> 32));
      float4 bx = bT[idx];
      float hw = __fmul_rn(bx.z, 0.5f);
      float hh = __fmul_rn(bx.w, 0.5f);
      vals[0] = __fsub_rn(bx.x, hw);
      vals[1] = __fsub_rn(bx.y, hh);
      vals[2] = __fadd_rn(bx.x, hw);
      vals[3] = __fadd_rn(bx.y, hh);
      vals[4] = score;
      vals[5] = (float)clsg[(size_t)b * NA + idx];
    }
#pragma unroll
    for (int q = 0; q < 6; ++q)
      out[((size_t)(b * MAXDET) + tid) * 6 + q] = vals[q];
  }
}

extern "C" void kernel_launch(void* const* d_in, const int* in_sizes, int n_in,
                              void* d_out, int out_size, void* d_ws, size_t ws_size,
                              hipStream_t stream) {
  (void)in_sizes; (void)n_in; (void)out_size; (void)ws_size;
  const float* pred = (const float*)d_in[0];
  const int* imgsz = (const int*)d_in[1];
  char* ws = (char*)d_ws;
  unsigned* sug = (unsigned*)(ws + OFF_SU);
  int* cls = (int*)(ws + OFF_CLS);
  float4* boxT = (float4*)(ws + OFF_BOX);
  float* out = (float*)d_out;

  score_kernel<<<dim3((NA + 255) / 256, NB), 256, 0, stream>>>(pred, sug, cls, boxT);
  fused_kernel<<<NB, 1024, 0, stream>>>(sug, cls, boxT, imgsz, out);
}